// Round 11
// baseline (203.113 us; speedup 1.0000x reference)
//
#include <hip/hip_runtime.h>
#include <math.h>

#define NU_F 0.0031830988618379067f
#define HS 136   // halves per H row: 17*8 -> 16B-aligned, odd 16B-stride = bank-balanced
#define TANH_C 2.8853900817779268f   // 2/ln(2): tanh(x) = 1 - 2/(2^(Cx)+1)

typedef __attribute__((ext_vector_type(8))) _Float16 half8;
typedef __attribute__((ext_vector_type(4))) _Float16 half4;
typedef __attribute__((ext_vector_type(16))) float f32x16;

// tanh via exp2 + fast rcp: ~5 VALU (2 on trans pipe). inf-safe: e=inf -> 1, e=0 -> -1.
__device__ __forceinline__ float fast_tanh(float x) {
    const float e = __builtin_amdgcn_exp2f(x * TANH_C);  // e^(2x)
    const float r = __builtin_amdgcn_rcpf(e + 1.f);
    return fmaf(-2.f, r, 1.f);
}

// tanh(x + b) with b pre-scaled by TANH_C: one fma instead of add+mul.
__device__ __forceinline__ float fast_tanh_pre(float x, float b2) {
    const float e = __builtin_amdgcn_exp2f(fmaf(x, TANH_C, b2));
    const float r = __builtin_amdgcn_rcpf(e + 1.f);
    return fmaf(-2.f, r, 1.f);
}

// DPP permute on f32 (returns permuted src; bound_ctrl=true)
template<int CTRL>
__device__ __forceinline__ float fdpp(float v) {
    union { float f; int i; } a, b;
    a.f = v;
    b.i = __builtin_amdgcn_update_dpp(0, a.i, CTRL, 0xF, 0xF, true);
    return b.f;
}

// ---------------------------------------------------------------------------
// Weight prep: W[l][k][n] fp32 -> k-tiled fp16:
//   idx = l*16384 + (k>>4)*2048 + n*16 + (k&15)
// A wave's per-kt B-read (16 halves/lane, n-contiguous) is one 1KB block.
// ---------------------------------------------------------------------------
__global__ void prep_kernel(const float* __restrict__ W1,
                            const float* __restrict__ W2,
                            const float* __restrict__ W3,
                            _Float16* __restrict__ ws)
{
    const int g = blockIdx.x * 256 + threadIdx.x;   // 0..49151
    const int l = g >> 14;
    const int r = g & 16383;
    const int n = r & 127;
    const int k = r >> 7;
    const float* W = (l == 0) ? W1 : (l == 1) ? W2 : W3;
    const float w = W[k * 128 + n];
    ws[l * 16384 + (k >> 4) * 2048 + n * 16 + (k & 15)] = (_Float16)w;
}

// ---------------------------------------------------------------------------
// R8 structure (M=128, 1x4 N-split, Z-trick, B software-pipeline, setprio,
// folded-bias trims, 4 blk/CU) + FUSED FINAL LAYER: layer 2's H3 never
// touches LDS. The epilogue registers (lane=col, 16 rows) are multiplied by
// W4[ncol] and reduced across the 16 col-lanes of each half via pure-DPP
// butterflies (xor1, xor2, row_ror:4, row_ror:8 — zero DS, zero shfl);
// 8 f32 partials/row land in a separate 4KB LDS array; final = 1 b128
// read + 3 adds. Removes 64 b16 stores + 8 b128 reads + 16 VMEM + 2
// barriers per wave, adds ~250 VALU (45%-busy, per-SIMD pipe).
// Blocks 0..4095: equation, 32 pts. Blocks 4096..4159: init/bound, 128 pts.
// ---------------------------------------------------------------------------
__launch_bounds__(256, 4)
__global__ void pinn_kernel(const float* __restrict__ tx_eq,
                            const float* __restrict__ tx_init,
                            const float* __restrict__ tx_bnd,
                            const float* __restrict__ W0, const float* __restrict__ b0,
                            const float* __restrict__ b1, const float* __restrict__ b2,
                            const float* __restrict__ b3,
                            const float* __restrict__ W4, const float* __restrict__ b4,
                            const _Float16* __restrict__ wt,
                            float* __restrict__ out)
{
    __shared__ _Float16 Hh[128][HS];   // 34.8 KB, in-place across layers 0/1
    __shared__ float   part[128][8];   // 4 KB: final-layer partials (no alias)

    const int tid   = threadIdx.x;
    const int blk   = blockIdx.x;
    const bool is_eq = (blk < 4096);
    const int w     = tid >> 6;
    const int lane  = tid & 63;
    const int col   = lane & 31;
    const int khalf = lane >> 5;
    const int ncol  = 32 * w + col;
    const int wofs  = ncol * 16 + khalf * 8;

    // ---- earliest VMEM: the point coordinates (oldest in queue) ----
    float tv, xv;
    if (is_eq) {
        const float2 t2 = ((const float2*)tx_eq)[blk * 32 + (tid >> 3)];
        tv = t2.x; xv = t2.y;
    } else {
        const int p  = tid >> 1;
        const int gp = (blk - 4096) * 128 + p;
        const float2* src = (gp < 4096) ? (const float2*)tx_init : (const float2*)tx_bnd;
        const int idx = (gp < 4096) ? gp : gp - 4096;
        const float2 t2 = src[idx];
        tv = t2.x; xv = t2.y;
    }

    // ---- layer-0 B prefetch: issued here, consumed after the input barrier ----
    const _Float16* ph = wt + wofs;
    half8 q0 = *(const half8*)(ph);
    half8 q1 = *(const half8*)(ph + 2048);
    half8 q2 = *(const half8*)(ph + 4096);
    half8 q3 = *(const half8*)(ph + 6144);
    half8 q4 = *(const half8*)(ph + 8192);
    half8 q5 = *(const half8*)(ph + 10240);
    half8 q6 = *(const half8*)(ph + 12288);
    half8 q7 = *(const half8*)(ph + 14336);

    // never-written zero C-operand (init once, reused all 3 layers)
    f32x16 Z;
    #pragma unroll
    for (int e = 0; e < 16; ++e) Z[e] = 0.f;

    // ---- input layer (K=2, pointwise, fp32) ----
    if (is_eq) {
        const int p  = tid >> 3;                 // 0..31
        const int f0 = (tid & 7) * 16;
        const int m0 = 4 * p;
        #pragma unroll
        for (int half = 0; half < 2; ++half) {
            const int fb = f0 + 8 * half;
            float vch[4][8];
            #pragma unroll
            for (int j = 0; j < 8; ++j) {
                const int f = fb + j;
                const float w0v = W0[f];             // dz/dt
                const float w1v = W0[128 + f];       // dz/dx
                const float z = fmaf(tv, w0v, fmaf(xv, w1v, b0[f]));
                const float a = fast_tanh(z);
                const float s = 1.f - a * a;
                const float v2 = s * w1v;
                vch[0][j] = a;
                vch[1][j] = s * w0v;
                vch[2][j] = v2;
                vch[3][j] = ((a * v2) * w1v) * -2.f;
            }
            #pragma unroll
            for (int c = 0; c < 4; ++c) {
                half8 hh;
                #pragma unroll
                for (int j = 0; j < 8; ++j) hh[j] = (_Float16)vch[c][j];
                *(half8*)&Hh[m0 + c][fb] = hh;
            }
        }
    } else {
        const int p  = tid >> 1;                 // 0..127 == row m
        const int f0 = (tid & 1) * 64;
        #pragma unroll
        for (int g = 0; g < 8; ++g) {
            half8 hh;
            #pragma unroll
            for (int j = 0; j < 8; ++j) {
                const int f = f0 + 8 * g + j;
                hh[j] = (_Float16)fast_tanh(fmaf(tv, W0[f], fmaf(xv, W0[128 + f], b0[f])));
            }
            *(half8*)&Hh[p][f0 + 8 * g] = hh;
        }
    }
    __syncthreads();

#define KSTEP0(Q)                                                             \
        {                                                                     \
            const int k0 = khalf * 8;                                         \
            const half8 ah0 = *(const half8*)&Hh[col][k0];                    \
            const half8 ah1 = *(const half8*)&Hh[32 + col][k0];               \
            const half8 ah2 = *(const half8*)&Hh[64 + col][k0];               \
            const half8 ah3 = *(const half8*)&Hh[96 + col][k0];               \
            acc0 = __builtin_amdgcn_mfma_f32_32x32x16_f16(ah0, Q, Z, 0, 0, 0); \
            acc1 = __builtin_amdgcn_mfma_f32_32x32x16_f16(ah1, Q, Z, 0, 0, 0); \
            acc2 = __builtin_amdgcn_mfma_f32_32x32x16_f16(ah2, Q, Z, 0, 0, 0); \
            acc3 = __builtin_amdgcn_mfma_f32_32x32x16_f16(ah3, Q, Z, 0, 0, 0); \
        }
#define KSTEP(KT, Q)                                                          \
        {                                                                     \
            const int k0 = KT * 16 + khalf * 8;                               \
            const half8 ah0 = *(const half8*)&Hh[col][k0];                    \
            const half8 ah1 = *(const half8*)&Hh[32 + col][k0];               \
            const half8 ah2 = *(const half8*)&Hh[64 + col][k0];               \
            const half8 ah3 = *(const half8*)&Hh[96 + col][k0];               \
            acc0 = __builtin_amdgcn_mfma_f32_32x32x16_f16(ah0, Q, acc0, 0, 0, 0); \
            acc1 = __builtin_amdgcn_mfma_f32_32x32x16_f16(ah1, Q, acc1, 0, 0, 0); \
            acc2 = __builtin_amdgcn_mfma_f32_32x32x16_f16(ah2, Q, acc2, 0, 0, 0); \
            acc3 = __builtin_amdgcn_mfma_f32_32x32x16_f16(ah3, Q, acc3, 0, 0, 0); \
        }

    // ---- layers 0 and 1: MFMA + activation epilogue + LDS transpose ----
    const float* barr[2] = {b1, b2};
    #pragma unroll 1
    for (int layer = 0; layer < 2; ++layer) {
        const float bias2 = barr[layer][ncol] * TANH_C;

        f32x16 acc0, acc1, acc2, acc3;
        __builtin_amdgcn_s_setprio(1);
        KSTEP0(q0) KSTEP(1, q1) KSTEP(2, q2) KSTEP(3, q3)
        KSTEP(4, q4) KSTEP(5, q5) KSTEP(6, q6) KSTEP(7, q7)
        __builtin_amdgcn_s_setprio(0);

        // next layer's B prefetch (layer 0 -> layer-1 W; layer 1 -> layer-2 W)
        ph += 16384;
        q0 = *(const half8*)(ph);
        q1 = *(const half8*)(ph + 2048);
        q2 = *(const half8*)(ph + 4096);
        q3 = *(const half8*)(ph + 6144);
        q4 = *(const half8*)(ph + 8192);
        q5 = *(const half8*)(ph + 10240);
        q6 = *(const half8*)(ph + 12288);
        q7 = *(const half8*)(ph + 14336);

        half4 h16[4][4];
        #pragma unroll
        for (int mt = 0; mt < 4; ++mt)
            #pragma unroll
            for (int g = 0; g < 4; ++g) {
                const float A0 = (mt == 0 ? acc0 : mt == 1 ? acc1 : mt == 2 ? acc2 : acc3)[4 * g + 0];
                const float A1 = (mt == 0 ? acc0 : mt == 1 ? acc1 : mt == 2 ? acc2 : acc3)[4 * g + 1];
                const float A2 = (mt == 0 ? acc0 : mt == 1 ? acc1 : mt == 2 ? acc2 : acc3)[4 * g + 2];
                const float A3 = (mt == 0 ? acc0 : mt == 1 ? acc1 : mt == 2 ? acc2 : acc3)[4 * g + 3];
                half4 hv;
                if (is_eq) {
                    const float t = fast_tanh_pre(A0, bias2);
                    const float s = 1.f - t * t;
                    const float sA2 = s * A2;
                    hv[0] = (_Float16)t;
                    hv[1] = (_Float16)(s * A1);
                    hv[2] = (_Float16)sA2;
                    hv[3] = (_Float16)fmaf(s, A3, -2.f * ((t * sA2) * A2));
                } else {
                    hv[0] = (_Float16)fast_tanh_pre(A0, bias2);
                    hv[1] = (_Float16)fast_tanh_pre(A1, bias2);
                    hv[2] = (_Float16)fast_tanh_pre(A2, bias2);
                    hv[3] = (_Float16)fast_tanh_pre(A3, bias2);
                }
                h16[mt][g] = hv;
            }

        __syncthreads();   // all reads of H done -> in-place overwrite safe

        #pragma unroll
        for (int mt = 0; mt < 4; ++mt)
            #pragma unroll
            for (int g = 0; g < 4; ++g) {
                const int mrow0 = mt * 32 + 8 * g + 4 * khalf;
                Hh[mrow0 + 0][ncol] = h16[mt][g][0];
                Hh[mrow0 + 1][ncol] = h16[mt][g][1];
                Hh[mrow0 + 2][ncol] = h16[mt][g][2];
                Hh[mrow0 + 3][ncol] = h16[mt][g][3];
            }
        __syncthreads();
    }

    // ---- layer 2 + fused W4 dot: H3 stays in registers ----
    {
        const float bias2 = b3[ncol] * TANH_C;
        const float w4c   = W4[ncol];

        f32x16 acc0, acc1, acc2, acc3;
        __builtin_amdgcn_s_setprio(1);
        KSTEP0(q0) KSTEP(1, q1) KSTEP(2, q2) KSTEP(3, q3)
        KSTEP(4, q4) KSTEP(5, q5) KSTEP(6, q6) KSTEP(7, q7)
        __builtin_amdgcn_s_setprio(0);

        // per m-tile: activation -> p = h*W4[ncol] -> 16-lane DPP reduction
        // (xor1, xor2, row_ror:4, row_ror:8 — each lane ends with the sum
        // over its 16-col half) -> lane (lane&15) selects value (g,e) and
        // writes part[mt*32+8g+4khalf+e][2w + half].
        const int  pc    = 2 * w + ((lane >> 4) & 1);
        const bool lb0   = (lane & 1) != 0;
        const bool lb1   = (lane & 2) != 0;
        const bool lb2   = (lane & 4) != 0;
        const bool lb3   = (lane & 8) != 0;
        #pragma unroll
        for (int mt = 0; mt < 4; ++mt) {
            float p[16];
            #pragma unroll
            for (int g = 0; g < 4; ++g) {
                const float A0 = (mt == 0 ? acc0 : mt == 1 ? acc1 : mt == 2 ? acc2 : acc3)[4 * g + 0];
                const float A1 = (mt == 0 ? acc0 : mt == 1 ? acc1 : mt == 2 ? acc2 : acc3)[4 * g + 1];
                const float A2 = (mt == 0 ? acc0 : mt == 1 ? acc1 : mt == 2 ? acc2 : acc3)[4 * g + 2];
                const float A3 = (mt == 0 ? acc0 : mt == 1 ? acc1 : mt == 2 ? acc2 : acc3)[4 * g + 3];
                float h0v, h1v, h2v, h3v;
                if (is_eq) {
                    const float t = fast_tanh_pre(A0, bias2);
                    const float s = 1.f - t * t;
                    const float sA2 = s * A2;
                    h0v = t;
                    h1v = s * A1;
                    h2v = sA2;
                    h3v = fmaf(s, A3, -2.f * ((t * sA2) * A2));
                } else {
                    h0v = fast_tanh_pre(A0, bias2);
                    h1v = fast_tanh_pre(A1, bias2);
                    h2v = fast_tanh_pre(A2, bias2);
                    h3v = fast_tanh_pre(A3, bias2);
                }
                // match the f16 rounding of the LDS path (absmax parity)
                p[4 * g + 0] = (float)(_Float16)h0v * w4c;
                p[4 * g + 1] = (float)(_Float16)h1v * w4c;
                p[4 * g + 2] = (float)(_Float16)h2v * w4c;
                p[4 * g + 3] = (float)(_Float16)h3v * w4c;
            }
            #pragma unroll
            for (int i = 0; i < 16; ++i) {
                p[i] += fdpp<0xB1>(p[i]);    // + lane^1  (quad_perm 1,0,3,2)
                p[i] += fdpp<0x4E>(p[i]);    // + lane^2  (quad_perm 2,3,0,1)
                p[i] += fdpp<0x124>(p[i]);   // + row_ror:4  (other quad pair)
                p[i] += fdpp<0x128>(p[i]);   // + row_ror:8  (remaining quads)
            }
            // select p[lane&15] via 15 cndmasks (static indices only)
            float t0[8], t1[4], t2[2];
            #pragma unroll
            for (int j = 0; j < 8; ++j) t0[j] = lb0 ? p[2 * j + 1] : p[2 * j];
            #pragma unroll
            for (int j = 0; j < 4; ++j) t1[j] = lb1 ? t0[2 * j + 1] : t0[2 * j];
            #pragma unroll
            for (int j = 0; j < 2; ++j) t2[j] = lb2 ? t1[2 * j + 1] : t1[2 * j];
            const float v = lb3 ? t2[1] : t2[0];
            const int row = mt * 32 + 8 * ((lane >> 2) & 3) + 4 * khalf + (lane & 3);
            part[row][pc] = v;
        }
    }
#undef KSTEP0
#undef KSTEP
    __syncthreads();

    // ---- final combine: thread pair (m = tid>>1, q = tid&1) sums its 4
    //      partials, pair-reduces, then the R8 shuffle tail.
    {
        const float b4v = b4[0];
        const int m = tid >> 1;
        const int q = tid & 1;
        const float4 pv = *(const float4*)&part[m][4 * q];
        float dot = (pv.x + pv.y) + (pv.z + pv.w);
        dot += __shfl_xor(dot, 1);   // full row-dot at both lanes of the pair

        if (is_eq) {
            // wave w holds rows [32w,32w+32) = points [8w,8w+8);
            // row r of point pl (=4pl+c) sits at lanes 8pl+2c (+q).
            const int base = (lane & 7) * 8;
            const float uu   = __shfl(dot, base + 0) + b4v;
            const float utv  = __shfl(dot, base + 2);
            const float uxv  = __shfl(dot, base + 4);
            const float uxxv = __shfl(dot, base + 6);
            if (lane < 8)
                out[blk * 32 + 8 * w + lane] = fmaf(uu, uxv, utv) - NU_F * uxxv;
        } else {
            if (q == 0)
                out[131072 + (blk - 4096) * 128 + m] = dot + b4v;
        }
    }
}

extern "C" void kernel_launch(void* const* d_in, const int* in_sizes, int n_in,
                              void* d_out, int out_size, void* d_ws, size_t ws_size,
                              hipStream_t stream)
{
    const float* tx_eq   = (const float*)d_in[0];
    const float* tx_init = (const float*)d_in[1];
    const float* tx_bnd  = (const float*)d_in[2];
    const float* W0 = (const float*)d_in[3];
    const float* b0 = (const float*)d_in[4];
    const float* W1 = (const float*)d_in[5];
    const float* b1 = (const float*)d_in[6];
    const float* W2 = (const float*)d_in[7];
    const float* b2 = (const float*)d_in[8];
    const float* W3 = (const float*)d_in[9];
    const float* b3 = (const float*)d_in[10];
    const float* W4 = (const float*)d_in[11];
    const float* b4 = (const float*)d_in[12];
    float* out = (float*)d_out;
    _Float16* wt = (_Float16*)d_ws;   // needs 98304 B

    hipLaunchKernelGGL(prep_kernel, dim3(192), dim3(256), 0, stream, W1, W2, W3, wt);
    // 4096 eq blocks (32 pts) + 64 ib blocks (128 pts)
    hipLaunchKernelGGL(pinn_kernel, dim3(4160), dim3(256), 0, stream,
                       tx_eq, tx_init, tx_bnd, W0, b0, b1, b2, b3, W4, b4,
                       (const _Float16*)wt, out);
}

// Round 12
// 159.280 us; speedup vs baseline: 1.2752x; 1.2752x over previous
//
#include <hip/hip_runtime.h>
#include <math.h>

#define NU_F 0.0031830988618379067f
#define HS 136   // halves per H row: 17*8 -> 16B-aligned, odd 16B-stride = bank-balanced
#define TANH_C 2.8853900817779268f   // 2/ln(2): tanh(x) = 1 - 2/(2^(Cx)+1)

typedef __attribute__((ext_vector_type(8))) _Float16 half8;
typedef __attribute__((ext_vector_type(4))) _Float16 half4;
typedef __attribute__((ext_vector_type(16))) float f32x16;

// tanh via exp2 + fast rcp: ~5 VALU (2 on trans pipe). inf-safe: e=inf -> 1, e=0 -> -1.
__device__ __forceinline__ float fast_tanh(float x) {
    const float e = __builtin_amdgcn_exp2f(x * TANH_C);  // e^(2x)
    const float r = __builtin_amdgcn_rcpf(e + 1.f);
    return fmaf(-2.f, r, 1.f);
}

// tanh(x + b) with b pre-scaled by TANH_C: one fma instead of add+mul.
__device__ __forceinline__ float fast_tanh_pre(float x, float b2) {
    const float e = __builtin_amdgcn_exp2f(fmaf(x, TANH_C, b2));
    const float r = __builtin_amdgcn_rcpf(e + 1.f);
    return fmaf(-2.f, r, 1.f);
}

// ---------------------------------------------------------------------------
// Weight prep: W[l][k][n] fp32 -> k-tiled fp16:
//   idx = l*16384 + (k>>4)*2048 + n*16 + (k&15)
// A wave's per-kt B-read (16 halves/lane, n-contiguous) is one 1KB block.
// ---------------------------------------------------------------------------
__global__ void prep_kernel(const float* __restrict__ W1,
                            const float* __restrict__ W2,
                            const float* __restrict__ W3,
                            _Float16* __restrict__ ws)
{
    const int g = blockIdx.x * 256 + threadIdx.x;   // 0..49151
    const int l = g >> 14;
    const int r = g & 16383;
    const int n = r & 127;
    const int k = r >> 7;
    const float* W = (l == 0) ? W1 : (l == 1) ? W2 : W3;
    const float w = W[k * 128 + n];
    ws[l * 16384 + (k >> 4) * 2048 + n * 16 + (k & 15)] = (_Float16)w;
}

// ---------------------------------------------------------------------------
// FINAL (R8): the measured optimum of the barrier-phased M=128 structure.
// Session ledger: occupancy up (R1/R5) null/spill; occupancy down (R4/R9)
// -10/-20%; DS-count cuts (R2/R7/R10/R11) null-to-spill; role-swap (R6)
// -150%. Only instruction/latency removals paid: Z-trick + B software-
// pipeline (R3, +7%), setprio + folded-bias + chain-rule re-assoc (R8, +1%).
// 60 VGPR + 64 AGPR = 124 <= 128 -> exactly the 4-waves/SIMD register tier;
// 34.8 KB LDS -> 4 blocks/CU = 16 waves/CU (measured optimum).
// Blocks 0..4095: equation, 32 pts (M=128 rows, m = 4p + channel).
// Blocks 4096..4159: init/bound forward-only, 128 pts (m = p).
// Wave w computes cols [32w,32w+32) for all 128 rows (mt=0..3).
// ---------------------------------------------------------------------------
__launch_bounds__(256, 4)
__global__ void pinn_kernel(const float* __restrict__ tx_eq,
                            const float* __restrict__ tx_init,
                            const float* __restrict__ tx_bnd,
                            const float* __restrict__ W0, const float* __restrict__ b0,
                            const float* __restrict__ b1, const float* __restrict__ b2,
                            const float* __restrict__ b3,
                            const float* __restrict__ W4, const float* __restrict__ b4,
                            const _Float16* __restrict__ wt,
                            float* __restrict__ out)
{
    __shared__ _Float16 Hh[128][HS];   // 34.8 KB, in-place across layers

    const int tid   = threadIdx.x;
    const int blk   = blockIdx.x;
    const bool is_eq = (blk < 4096);
    const int w     = tid >> 6;
    const int lane  = tid & 63;
    const int col   = lane & 31;
    const int khalf = lane >> 5;
    const int ncol  = 32 * w + col;
    const int wofs  = ncol * 16 + khalf * 8;

    // ---- earliest VMEM: the point coordinates (oldest in queue) ----
    float tv, xv;
    if (is_eq) {
        const float2 t2 = ((const float2*)tx_eq)[blk * 32 + (tid >> 3)];
        tv = t2.x; xv = t2.y;
    } else {
        const int p  = tid >> 1;
        const int gp = (blk - 4096) * 128 + p;
        const float2* src = (gp < 4096) ? (const float2*)tx_init : (const float2*)tx_bnd;
        const int idx = (gp < 4096) ? gp : gp - 4096;
        const float2 t2 = src[idx];
        tv = t2.x; xv = t2.y;
    }

    // ---- layer-0 B prefetch: issued here, consumed after the input barrier ----
    const _Float16* ph = wt + wofs;
    half8 q0 = *(const half8*)(ph);
    half8 q1 = *(const half8*)(ph + 2048);
    half8 q2 = *(const half8*)(ph + 4096);
    half8 q3 = *(const half8*)(ph + 6144);
    half8 q4 = *(const half8*)(ph + 8192);
    half8 q5 = *(const half8*)(ph + 10240);
    half8 q6 = *(const half8*)(ph + 12288);
    half8 q7 = *(const half8*)(ph + 14336);

    // never-written zero C-operand (init once, reused all 3 layers)
    f32x16 Z;
    #pragma unroll
    for (int e = 0; e < 16; ++e) Z[e] = 0.f;

    // ---- input layer (K=2, pointwise, fp32) ----
    if (is_eq) {
        const int p  = tid >> 3;                 // 0..31
        const int f0 = (tid & 7) * 16;
        const int m0 = 4 * p;
        #pragma unroll
        for (int half = 0; half < 2; ++half) {
            const int fb = f0 + 8 * half;
            float vch[4][8];
            #pragma unroll
            for (int j = 0; j < 8; ++j) {
                const int f = fb + j;
                const float w0v = W0[f];             // dz/dt
                const float w1v = W0[128 + f];       // dz/dx
                const float z = fmaf(tv, w0v, fmaf(xv, w1v, b0[f]));
                const float a = fast_tanh(z);
                const float s = 1.f - a * a;
                const float v2 = s * w1v;
                vch[0][j] = a;
                vch[1][j] = s * w0v;
                vch[2][j] = v2;
                vch[3][j] = ((a * v2) * w1v) * -2.f;
            }
            #pragma unroll
            for (int c = 0; c < 4; ++c) {
                half8 hh;
                #pragma unroll
                for (int j = 0; j < 8; ++j) hh[j] = (_Float16)vch[c][j];
                *(half8*)&Hh[m0 + c][fb] = hh;
            }
        }
    } else {
        const int p  = tid >> 1;                 // 0..127 == row m
        const int f0 = (tid & 1) * 64;
        #pragma unroll
        for (int g = 0; g < 8; ++g) {
            half8 hh;
            #pragma unroll
            for (int j = 0; j < 8; ++j) {
                const int f = f0 + 8 * g + j;
                hh[j] = (_Float16)fast_tanh(fmaf(tv, W0[f], fmaf(xv, W0[128 + f], b0[f])));
            }
            *(half8*)&Hh[p][f0 + 8 * g] = hh;
        }
    }
    __syncthreads();

    const float* barr[3] = {b1, b2, b3};

    #pragma unroll 1
    for (int layer = 0; layer < 3; ++layer) {
        const float bias2 = barr[layer][ncol] * TANH_C;

        f32x16 acc0, acc1, acc2, acc3;

#define KSTEP0(Q)                                                             \
        {                                                                     \
            const int k0 = khalf * 8;                                         \
            const half8 ah0 = *(const half8*)&Hh[col][k0];                    \
            const half8 ah1 = *(const half8*)&Hh[32 + col][k0];               \
            const half8 ah2 = *(const half8*)&Hh[64 + col][k0];               \
            const half8 ah3 = *(const half8*)&Hh[96 + col][k0];               \
            acc0 = __builtin_amdgcn_mfma_f32_32x32x16_f16(ah0, Q, Z, 0, 0, 0); \
            acc1 = __builtin_amdgcn_mfma_f32_32x32x16_f16(ah1, Q, Z, 0, 0, 0); \
            acc2 = __builtin_amdgcn_mfma_f32_32x32x16_f16(ah2, Q, Z, 0, 0, 0); \
            acc3 = __builtin_amdgcn_mfma_f32_32x32x16_f16(ah3, Q, Z, 0, 0, 0); \
        }
#define KSTEP(KT, Q)                                                          \
        {                                                                     \
            const int k0 = KT * 16 + khalf * 8;                               \
            const half8 ah0 = *(const half8*)&Hh[col][k0];                    \
            const half8 ah1 = *(const half8*)&Hh[32 + col][k0];               \
            const half8 ah2 = *(const half8*)&Hh[64 + col][k0];               \
            const half8 ah3 = *(const half8*)&Hh[96 + col][k0];               \
            acc0 = __builtin_amdgcn_mfma_f32_32x32x16_f16(ah0, Q, acc0, 0, 0, 0); \
            acc1 = __builtin_amdgcn_mfma_f32_32x32x16_f16(ah1, Q, acc1, 0, 0, 0); \
            acc2 = __builtin_amdgcn_mfma_f32_32x32x16_f16(ah2, Q, acc2, 0, 0, 0); \
            acc3 = __builtin_amdgcn_mfma_f32_32x32x16_f16(ah3, Q, acc3, 0, 0, 0); \
        }
        __builtin_amdgcn_s_setprio(1);
        KSTEP0(q0) KSTEP(1, q1) KSTEP(2, q2) KSTEP(3, q3)
        KSTEP(4, q4) KSTEP(5, q5) KSTEP(6, q6) KSTEP(7, q7)
        __builtin_amdgcn_s_setprio(0);
#undef KSTEP0
#undef KSTEP

        // ---- next layer's B prefetch: q-regs just consumed, reload now so
        // L2 latency hides under epilogue compute + both barriers.
        if (layer < 2) {
            ph += 16384;
            q0 = *(const half8*)(ph);
            q1 = *(const half8*)(ph + 2048);
            q2 = *(const half8*)(ph + 4096);
            q3 = *(const half8*)(ph + 6144);
            q4 = *(const half8*)(ph + 8192);
            q5 = *(const half8*)(ph + 10240);
            q6 = *(const half8*)(ph + 12288);
            q7 = *(const half8*)(ph + 14336);
        }

        // epilogue COMPUTE (registers only, before the barrier). C-layout:
        // reg group 4g..4g+3 = rows mt*32+8g+4khalf+{0..3} = the 4 derivative
        // channels of one point (eq) -> chain rule in registers.
        half4 h16[4][4];
        #pragma unroll
        for (int mt = 0; mt < 4; ++mt)
            #pragma unroll
            for (int g = 0; g < 4; ++g) {
                const float A0 = (mt == 0 ? acc0 : mt == 1 ? acc1 : mt == 2 ? acc2 : acc3)[4 * g + 0];
                const float A1 = (mt == 0 ? acc0 : mt == 1 ? acc1 : mt == 2 ? acc2 : acc3)[4 * g + 1];
                const float A2 = (mt == 0 ? acc0 : mt == 1 ? acc1 : mt == 2 ? acc2 : acc3)[4 * g + 2];
                const float A3 = (mt == 0 ? acc0 : mt == 1 ? acc1 : mt == 2 ? acc2 : acc3)[4 * g + 3];
                half4 hv;
                if (is_eq) {
                    const float t = fast_tanh_pre(A0, bias2);
                    const float s = 1.f - t * t;
                    const float sA2 = s * A2;
                    hv[0] = (_Float16)t;
                    hv[1] = (_Float16)(s * A1);
                    hv[2] = (_Float16)sA2;
                    hv[3] = (_Float16)fmaf(s, A3, -2.f * ((t * sA2) * A2));
                } else {
                    hv[0] = (_Float16)fast_tanh_pre(A0, bias2);
                    hv[1] = (_Float16)fast_tanh_pre(A1, bias2);
                    hv[2] = (_Float16)fast_tanh_pre(A2, bias2);
                    hv[3] = (_Float16)fast_tanh_pre(A3, bias2);
                }
                h16[mt][g] = hv;
            }

        __syncthreads();   // all reads of H done -> in-place overwrite safe

        // epilogue STORE (the only work between the two barriers)
        #pragma unroll
        for (int mt = 0; mt < 4; ++mt)
            #pragma unroll
            for (int g = 0; g < 4; ++g) {
                const int mrow0 = mt * 32 + 8 * g + 4 * khalf;
                Hh[mrow0 + 0][ncol] = h16[mt][g][0];
                Hh[mrow0 + 1][ncol] = h16[mt][g][1];
                Hh[mrow0 + 2][ncol] = h16[mt][g][2];
                Hh[mrow0 + 3][ncol] = h16[mt][g][3];
            }
        __syncthreads();
    }

    // ---- final layer (128 -> 1): thread t reduces k-half (t&1) of row t>>1
    {
        const float b4v = b4[0];
        const int m = tid >> 1;
        const int q = tid & 1;
        float dot = 0.f;
        #pragma unroll
        for (int g = 0; g < 8; ++g) {
            const int f = 64 * q + 8 * g;
            const half8 hh = *(const half8*)&Hh[m][f];
            const float4 wa = *(const float4*)&W4[f];
            const float4 wb = *(const float4*)&W4[f + 4];
            dot = fmaf((float)hh[0], wa.x, dot);
            dot = fmaf((float)hh[1], wa.y, dot);
            dot = fmaf((float)hh[2], wa.z, dot);
            dot = fmaf((float)hh[3], wa.w, dot);
            dot = fmaf((float)hh[4], wb.x, dot);
            dot = fmaf((float)hh[5], wb.y, dot);
            dot = fmaf((float)hh[6], wb.z, dot);
            dot = fmaf((float)hh[7], wb.w, dot);
        }
        dot += __shfl_xor(dot, 1);   // full row-dot at both lanes of the pair

        if (is_eq) {
            // wave w holds rows [32w,32w+32) = points [8w,8w+8);
            // row r of point pl (=4pl+c) sits at lanes 8pl+2c (+q).
            const int base = (lane & 7) * 8;
            const float uu   = __shfl(dot, base + 0) + b4v;
            const float utv  = __shfl(dot, base + 2);
            const float uxv  = __shfl(dot, base + 4);
            const float uxxv = __shfl(dot, base + 6);
            if (lane < 8)
                out[blk * 32 + 8 * w + lane] = fmaf(uu, uxv, utv) - NU_F * uxxv;
        } else {
            if (q == 0)
                out[131072 + (blk - 4096) * 128 + m] = dot + b4v;
        }
    }
}

extern "C" void kernel_launch(void* const* d_in, const int* in_sizes, int n_in,
                              void* d_out, int out_size, void* d_ws, size_t ws_size,
                              hipStream_t stream)
{
    const float* tx_eq   = (const float*)d_in[0];
    const float* tx_init = (const float*)d_in[1];
    const float* tx_bnd  = (const float*)d_in[2];
    const float* W0 = (const float*)d_in[3];
    const float* b0 = (const float*)d_in[4];
    const float* W1 = (const float*)d_in[5];
    const float* b1 = (const float*)d_in[6];
    const float* W2 = (const float*)d_in[7];
    const float* b2 = (const float*)d_in[8];
    const float* W3 = (const float*)d_in[9];
    const float* b3 = (const float*)d_in[10];
    const float* W4 = (const float*)d_in[11];
    const float* b4 = (const float*)d_in[12];
    float* out = (float*)d_out;
    _Float16* wt = (_Float16*)d_ws;   // needs 98304 B

    hipLaunchKernelGGL(prep_kernel, dim3(192), dim3(256), 0, stream, W1, W2, W3, wt);
    // 4096 eq blocks (32 pts) + 64 ib blocks (128 pts)
    hipLaunchKernelGGL(pinn_kernel, dim3(4160), dim3(256), 0, stream,
                       tx_eq, tx_init, tx_bnd, W0, b0, b1, b2, b3, W4, b4,
                       (const _Float16*)wt, out);
}